// Round 7
// baseline (12146.025 us; speedup 1.0000x reference)
//
#include <hip/hip_runtime.h>
#include <hip/hip_bf16.h>
#include <hip/hip_cooperative_groups.h>

namespace cg = cooperative_groups;

#define BB 128   // batch
#define LL 512   // seq len
#define HH 2048  // hidden
#define EE 128   // embed
#define VV 96    // vocab
#define BBHH (BB * HH)
#define NBLK 256
#define NTHR 1024
#define GTOT (NBLK * NTHR)

typedef short bf16x8 __attribute__((ext_vector_type(8)));
typedef float f32x4 __attribute__((ext_vector_type(4)));

__device__ __forceinline__ unsigned short f2bf(float f) {
    union { float f; unsigned int u; } c; c.f = f;
    unsigned int u = c.u;
    return (unsigned short)((u + 0x7FFFu + ((u >> 16) & 1u)) >> 16);  // RNE
}

__device__ __forceinline__ unsigned long long ld_dev(const unsigned long long* p) {
    return __hip_atomic_load(p, __ATOMIC_RELAXED, __HIP_MEMORY_SCOPE_AGENT);
}
__device__ __forceinline__ void st_dev(unsigned short* p, unsigned short v) {
    __hip_atomic_store(p, v, __ATOMIC_RELAXED, __HIP_MEMORY_SCOPE_AGENT);
}
__device__ __forceinline__ unsigned ld_dev32(const unsigned* p) {
    return __hip_atomic_load(p, __ATOMIC_RELAXED, __HIP_MEMORY_SCOPE_AGENT);
}
__device__ __forceinline__ void st_dev32(unsigned* p, unsigned v) {
    __hip_atomic_store(p, v, __ATOMIC_RELAXED, __HIP_MEMORY_SCOPE_AGENT);
}

// Contention-free, fence-free slot barrier (R6). sc1 ops bypass non-coherent
// per-XCD L2s; __syncthreads drains each wave's vmcnt (sc1 h-stores acked at
// the coherence point) before arrival. Threads 0..255 poll one slot each.
__device__ __forceinline__ void gridbar(unsigned* slots, unsigned epoch,
                                        int bid, int tid) {
    __syncthreads();
    if (tid == 0) {
        asm volatile("s_waitcnt vmcnt(0)" ::: "memory");
        st_dev32(&slots[bid], epoch);
    }
    if (tid < NBLK) {
        while (ld_dev32(&slots[tid]) < epoch) { /* busy spin */ }
    }
    __syncthreads();
}

// Persistent cooperative RNN. Grid = 256 blocks x 1024 threads (16 waves =
// 4 waves/SIMD -> real latency hiding; R2-6 ran 1 wave/SIMD and were bound by
// sc1-load latency). Block (bm,bn) owns 64 batch rows x 16 hidden cols.
// K is split 4 ways across wave groups (kg=0..3, K-slice of 512); partial
// accumulators reduced through 12 KB LDS. W_hh slice (16x2048 bf16 = 64 KB)
// in LDS, MFMA-B-fragment-linear. h ping-pongs between two global buffers via
// sc1 ops; one slot barrier per step. Duty blocks (bn<6) fuse the logits GEMM
// one step behind, reusing the same A fragments.
__global__ __launch_bounds__(1024, 4)
void rnn_coop(const int* __restrict__ x, const float* __restrict__ hidden,
              const float* __restrict__ emb, const float* __restrict__ W_xh,
              const float* __restrict__ W_hh, const float* __restrict__ b_h,
              const float* __restrict__ W_hy, const float* __restrict__ b_y,
              float* __restrict__ projE, unsigned short* __restrict__ w_hy_frag,
              unsigned short* __restrict__ hbuf, unsigned* __restrict__ bar,
              float* __restrict__ out_logits, float* __restrict__ out_final)
{
    __shared__ __align__(16) unsigned short ldsB[4096 * 8];  // 64 KB W_hh tile
    __shared__ __align__(16) f32x4 ldsR[3 * 4 * 64];          // 12 KB K-reduce

    const int tid  = threadIdx.x;
    const int bid  = blockIdx.x;
    const int gtid = bid * NTHR + tid;

    const int bm = bid >> 7;            // 0..1
    const int bn = bid & 127;           // 0..127
    const int m0 = bm * 64;
    const int n0 = bn * 16;

    // ---- barrier slots = 0 (ws re-poisoned 0xAA before every call) ----
    if (bid == 0 && tid < NBLK) st_dev32(&bar[tid], 0u);

    // ---- LDS fill: W_hh slice -> bf16, fragment-linear (one-time) ----
    for (int c = tid; c < 4096; c += NTHR) {
        int i  = c >> 6;
        int l  = c & 63;
        int nl = l & 15;
        int qq = l >> 4;
        const float* src = W_hh + (size_t)(n0 + nl) * HH + (size_t)i * 32 + qq * 8;
        unsigned short tmp[8];
        #pragma unroll
        for (int j = 0; j < 8; ++j) tmp[j] = f2bf(src[j]);
        #pragma unroll
        for (int j = 0; j < 8; ++j) ldsB[c * 8 + j] = tmp[j];
    }

    // ---- projE[v][h] = b_h[h] + emb[v][:] . W_xh[h][:]  (f32, exact) ----
    for (int i = gtid; i < VV * HH; i += GTOT) {
        int v  = i >> 11;
        int hc = i & (HH - 1);
        const float4* ep = (const float4*)(emb + (size_t)v * EE);
        const float4* wp = (const float4*)(W_xh + (size_t)hc * EE);
        float s = b_h[hc];
        #pragma unroll 8
        for (int e = 0; e < EE / 4; ++e) {
            float4 a = ep[e], b = wp[e];
            s += a.x * b.x + a.y * b.y + a.z * b.z + a.w * b.w;
        }
        projE[i] = s;
    }
    // ---- W_hy -> bf16, fragment-linear per 16-vocab tile ----
    for (int idx = gtid; idx < VV * HH; idx += GTOT) {
        int vt  = idx >> 15;
        int rem = idx & 32767;
        int c   = rem >> 3;
        int j   = rem & 7;
        int l   = c & 63;
        int i   = c >> 6;
        int v   = vt * 16 + (l & 15);
        int k   = i * 32 + (l >> 4) * 8 + j;
        w_hy_frag[idx] = f2bf(W_hy[(size_t)v * HH + k]);
    }
    // ---- h_0 (bf16) into ping buffer 0 ----
    for (int i = gtid; i < BBHH; i += GTOT) hbuf[i] = f2bf(hidden[i]);

    __syncthreads();
    cg::grid_group grid = cg::this_grid();
    __threadfence();
    grid.sync();   // one-time: publishes setup writes (incl. zeroed slots)

    const int W    = tid >> 6;     // wave 0..15
    const int kg   = W >> 2;       // K-group 0..3 (K slice of 512)
    const int wr   = W & 3;        // row-tile 0..3 (rows m0 + wr*16)
    const int lane = tid & 63;
    const int col  = lane & 15;
    const int q    = lane >> 4;
    const int am   = m0 + wr * 16 + col;   // A-fragment row (batch index)
    const int n    = n0 + col;             // output hidden column
    const bf16x8* ldsB8 = (const bf16x8*)ldsB;

    const bool duty = (bn < 6);
    const int  v0   = bn * 16;
    const bf16x8* Hyp = (const bf16x8*)w_hy_frag + (size_t)bn * 4096 + lane;
    const float by = duty ? b_y[v0 + col] : 0.f;

    // kg0 threads own the epilogue; prefetch first step's projE values
    int   mrow[4] = {0, 0, 0, 0};
    float pv[4]   = {0.f, 0.f, 0.f, 0.f};
    if (kg == 0) {
        #pragma unroll
        for (int r = 0; r < 4; ++r) {
            mrow[r] = m0 + wr * 16 + q * 4 + r;
            int tok = x[(size_t)mrow[r] * LL];
            pv[r]   = projE[(size_t)tok * HH + n];
        }
    }

    for (int t = 0; t < LL; ++t) {
        const unsigned short* hp = hbuf + (size_t)(t & 1) * BBHH;
        unsigned short* hn       = hbuf + (size_t)((t + 1) & 1) * BBHH;
        const unsigned long long* Ap8 =
            (const unsigned long long*)(hp + (size_t)am * HH + (size_t)kg * 512) + q * 2;

        f32x4 acc  = {0.f, 0.f, 0.f, 0.f};
        f32x4 accL = {0.f, 0.f, 0.f, 0.f};
        const bool dutyL = duty && (t > 0);

        #pragma unroll
        for (int half = 0; half < 2; ++half) {
            // batch-load 8 A fragments (16 outstanding sc1 dwordx2 loads)
            union { unsigned long long u[2]; bf16x8 v; } A[8];
            #pragma unroll
            for (int j = 0; j < 8; ++j) {
                int i = half * 8 + j;
                A[j].u[0] = ld_dev(Ap8 + (size_t)i * 8);
                A[j].u[1] = ld_dev(Ap8 + (size_t)i * 8 + 1);
            }
            #pragma unroll
            for (int j = 0; j < 8; ++j) {
                int ig = kg * 16 + half * 8 + j;
                acc = __builtin_amdgcn_mfma_f32_16x16x32_bf16(A[j].v,
                        ldsB8[ig * 64 + lane], acc, 0, 0, 0);
            }
            if (dutyL) {
                #pragma unroll
                for (int j = 0; j < 8; ++j) {
                    int ig = kg * 16 + half * 8 + j;
                    accL = __builtin_amdgcn_mfma_f32_16x16x32_bf16(A[j].v,
                            Hyp[ig * 64], accL, 0, 0, 0);
                }
            }
        }

        // ---- K-reduce acc through LDS ----
        if (kg > 0) ldsR[(kg - 1) * 256 + wr * 64 + lane] = acc;
        __syncthreads();
        if (kg == 0) {
            acc += ldsR[0 * 256 + wr * 64 + lane];
            acc += ldsR[1 * 256 + wr * 64 + lane];
            acc += ldsR[2 * 256 + wr * 64 + lane];
        }
        if (dutyL) {   // block-uniform branch; second reduce pass for accL
            __syncthreads();   // kg0's acc reads done before overwrite
            if (kg > 0) ldsR[(kg - 1) * 256 + wr * 64 + lane] = accL;
            __syncthreads();
            if (kg == 0) {
                accL += ldsR[0 * 256 + wr * 64 + lane];
                accL += ldsR[1 * 256 + wr * 64 + lane];
                accL += ldsR[2 * 256 + wr * 64 + lane];
            }
        }

        if (kg == 0) {
            // h epilogue: C/D layout col=lane&15, row=(lane>>4)*4+r
            #pragma unroll
            for (int r = 0; r < 4; ++r) {
                float v = acc[r] + pv[r];
                v = fminf(fmaxf(v, -15.f), 15.f);
                float e2 = __expf(2.f * v);
                float hv = (e2 - 1.f) / (e2 + 1.f);   // tanh
                st_dev(&hn[(size_t)mrow[r] * HH + n], f2bf(hv));
                if (t == LL - 1) out_final[(size_t)mrow[r] * HH + n] = hv;
            }
            if (dutyL) {
                #pragma unroll
                for (int r = 0; r < 4; ++r) {
                    out_logits[(size_t)mrow[r] * (LL * VV)
                               + (size_t)(t - 1) * VV + v0 + col] = accL[r] + by;
                }
            }
            // prefetch next step's projE values (hides behind barrier)
            if (t + 1 < LL) {
                #pragma unroll
                for (int r = 0; r < 4; ++r) {
                    int tok = x[(size_t)mrow[r] * LL + t + 1];
                    pv[r]   = projE[(size_t)tok * HH + n];
                }
            }
        }
        gridbar(bar, (unsigned)(t + 1), bid, tid);
    }

    // ---- logits for h_LL -> position LL-1 (final h in buffer 0) ----
    if (duty) {
        const unsigned long long* Ap8 =
            (const unsigned long long*)(hbuf + (size_t)am * HH + (size_t)kg * 512) + q * 2;
        f32x4 accL = {0.f, 0.f, 0.f, 0.f};
        #pragma unroll
        for (int half = 0; half < 2; ++half) {
            union { unsigned long long u[2]; bf16x8 v; } A[8];
            #pragma unroll
            for (int j = 0; j < 8; ++j) {
                int i = half * 8 + j;
                A[j].u[0] = ld_dev(Ap8 + (size_t)i * 8);
                A[j].u[1] = ld_dev(Ap8 + (size_t)i * 8 + 1);
            }
            #pragma unroll
            for (int j = 0; j < 8; ++j) {
                int ig = kg * 16 + half * 8 + j;
                accL = __builtin_amdgcn_mfma_f32_16x16x32_bf16(A[j].v,
                        Hyp[ig * 64], accL, 0, 0, 0);
            }
        }
        if (kg > 0) ldsR[(kg - 1) * 256 + wr * 64 + lane] = accL;
        __syncthreads();
        if (kg == 0) {
            accL += ldsR[0 * 256 + wr * 64 + lane];
            accL += ldsR[1 * 256 + wr * 64 + lane];
            accL += ldsR[2 * 256 + wr * 64 + lane];
            #pragma unroll
            for (int r = 0; r < 4; ++r) {
                out_logits[(size_t)mrow[r] * (LL * VV)
                           + (size_t)(LL - 1) * VV + v0 + col] = accL[r] + by;
            }
        }
    }
}

extern "C" void kernel_launch(void* const* d_in, const int* in_sizes, int n_in,
                              void* d_out, int out_size, void* d_ws, size_t ws_size,
                              hipStream_t stream) {
    const int*   x      = (const int*)  d_in[0];
    const float* hidden = (const float*)d_in[1];
    const float* emb    = (const float*)d_in[2];
    const float* W_xh   = (const float*)d_in[3];
    const float* W_hh   = (const float*)d_in[4];
    const float* b_h    = (const float*)d_in[5];
    const float* W_hy   = (const float*)d_in[6];
    const float* b_y    = (const float*)d_in[7];

    float* out_logits = (float*)d_out;                          // [B][L][V]
    float* out_final  = out_logits + (size_t)BB * LL * VV;      // [B][H]

    // workspace: 768 KB projE + 384 KB w_hy_frag + 1 MB h ping-pong + slots
    char* ws = (char*)d_ws;
    float* projE              = (float*)ws;
    unsigned short* w_hy_frag = (unsigned short*)(ws + 786432);
    unsigned short* hbuf      = (unsigned short*)(ws + 786432 + 393216);
    unsigned* bar             = (unsigned*)(ws + 786432 + 393216 + 2 * BBHH * 2);

    void* args[] = { (void*)&x, (void*)&hidden, (void*)&emb, (void*)&W_xh,
                     (void*)&W_hh, (void*)&b_h, (void*)&W_hy, (void*)&b_y,
                     (void*)&projE, (void*)&w_hy_frag, (void*)&hbuf,
                     (void*)&bar, (void*)&out_logits, (void*)&out_final };
    hipLaunchCooperativeKernel((const void*)rnn_coop, dim3(NBLK), dim3(NTHR),
                               args, 0, stream);
}

// Round 8
// 8413.830 us; speedup vs baseline: 1.4436x; 1.4436x over previous
//
#include <hip/hip_runtime.h>
#include <hip/hip_bf16.h>

#define BB 128   // batch
#define LL 512   // seq len
#define HH 2048  // hidden
#define EE 128   // embed
#define VV 96    // vocab
#define BBHH (BB * HH)

typedef short bf16x8 __attribute__((ext_vector_type(8)));
typedef float f32x4 __attribute__((ext_vector_type(4)));

__device__ __forceinline__ unsigned short f2bf(float f) {
    union { float f; unsigned int u; } c; c.f = f;
    unsigned int u = c.u;
    return (unsigned short)((u + 0x7FFFu + ((u >> 16) & 1u)) >> 16);  // RNE
}

// ---------------------------------------------------------------------------
// Setup: pack W_hh and W_hy into MFMA-B-fragment-linear bf16 tiles, compute
// projE[v][h] = b_h[h] + emb[v][:].W_xh[h][:] (fp32), pack h_0 to bf16.
// Fragment layout per 16-col tile: chunk c = i*64 + l holds
// W[tile*16 + (l&15)][i*32 + (l>>4)*8 + j], j=0..7  -> lane l reads 16 B
// contiguous at (i*64+l)*16 bytes: perfectly coalesced per wave.
// ---------------------------------------------------------------------------
__global__ __launch_bounds__(256)
void setup_kernel(const int* __restrict__ x, const float* __restrict__ hidden,
                  const float* __restrict__ emb, const float* __restrict__ W_xh,
                  const float* __restrict__ W_hh, const float* __restrict__ b_h,
                  const float* __restrict__ W_hy,
                  float* __restrict__ projE,
                  unsigned short* __restrict__ w_hh_frag,
                  unsigned short* __restrict__ w_hy_frag,
                  unsigned short* __restrict__ hbuf)
{
    const int gtid = blockIdx.x * 256 + threadIdx.x;   // 0..262143
    const int GT   = gridDim.x * 256;

    // W_hh -> fragment-linear bf16 (128 tiles x 32768 elems = 4 Mi elems)
    for (int idx = gtid; idx < HH * HH; idx += GT) {
        int tile = idx >> 15;           // 0..127
        int rem  = idx & 32767;
        int c    = rem >> 3;
        int j    = rem & 7;
        int l    = c & 63;
        int i    = c >> 6;
        int row  = tile * 16 + (l & 15);
        int k    = i * 32 + (l >> 4) * 8 + j;
        w_hh_frag[idx] = f2bf(W_hh[(size_t)row * HH + k]);
    }
    // W_hy -> fragment-linear bf16 (6 tiles)
    for (int idx = gtid; idx < VV * HH; idx += GT) {
        int tile = idx >> 15;
        int rem  = idx & 32767;
        int c    = rem >> 3;
        int j    = rem & 7;
        int l    = c & 63;
        int i    = c >> 6;
        int row  = tile * 16 + (l & 15);
        int k    = i * 32 + (l >> 4) * 8 + j;
        w_hy_frag[idx] = f2bf(W_hy[(size_t)row * HH + k]);
    }
    // projE (fp32, exact)
    for (int i = gtid; i < VV * HH; i += GT) {
        int v  = i >> 11;
        int hc = i & (HH - 1);
        const float4* ep = (const float4*)(emb + (size_t)v * EE);
        const float4* wp = (const float4*)(W_xh + (size_t)hc * EE);
        float s = b_h[hc];
        #pragma unroll 8
        for (int e = 0; e < EE / 4; ++e) {
            float4 a = ep[e], b = wp[e];
            s += a.x * b.x + a.y * b.y + a.z * b.z + a.w * b.w;
        }
        projE[i] = s;
    }
    // h_0 -> bf16 into ping buffer 0
    for (int i = gtid; i < BBHH; i += GT) hbuf[i] = f2bf(hidden[i]);
}

// ---------------------------------------------------------------------------
// One timestep: h_next = tanh(projE[x_t] + h W_hh^T), fused logits for
// position t-1 on duty blocks (bn<6) reusing the same A fragments.
// Grid 256 = 2 bm (64 batch rows) x 128 bn (16 hidden cols); 4 waves/block,
// wave w owns rows m0+w*16. All loads/stores are NORMAL cached ops — kernel
// boundaries provide the cross-XCD visibility (stream order), no sc1/fences.
// ---------------------------------------------------------------------------
__global__ __launch_bounds__(256)
void step_kernel(const int* __restrict__ x, const float* __restrict__ projE,
                 const unsigned short* __restrict__ w_hh_frag,
                 const unsigned short* __restrict__ w_hy_frag,
                 const float* __restrict__ b_y,
                 const unsigned short* __restrict__ hp,
                 unsigned short* __restrict__ hn,
                 float* __restrict__ out_logits, float* __restrict__ out_final,
                 int t)
{
    const int tid  = threadIdx.x;
    const int bid  = blockIdx.x;
    const int bm   = bid >> 7;
    const int bn   = bid & 127;
    const int m0   = bm * 64;
    const int n0   = bn * 16;

    const int w    = tid >> 6;
    const int lane = tid & 63;
    const int col  = lane & 15;
    const int q    = lane >> 4;
    const int am   = m0 + w * 16 + col;    // A-fragment row (batch index)
    const int n    = n0 + col;             // output hidden column

    const bf16x8* Ap  = (const bf16x8*)(hp + (size_t)am * HH + q * 8);
    const bf16x8* Bp  = (const bf16x8*)w_hh_frag + (size_t)bn * 4096 + lane;
    const bool duty   = (bn < 6) && (t > 0);
    const bf16x8* Hyp = (const bf16x8*)w_hy_frag + (size_t)bn * 4096 + lane;

    f32x4 acc  = {0.f, 0.f, 0.f, 0.f};
    f32x4 accL = {0.f, 0.f, 0.f, 0.f};

    if (duty) {
        #pragma unroll 4
        for (int i = 0; i < 64; ++i) {
            bf16x8 a  = Ap[i * 4];
            bf16x8 b  = Bp[i * 64];
            bf16x8 bl = Hyp[i * 64];
            acc  = __builtin_amdgcn_mfma_f32_16x16x32_bf16(a, b,  acc,  0, 0, 0);
            accL = __builtin_amdgcn_mfma_f32_16x16x32_bf16(a, bl, accL, 0, 0, 0);
        }
    } else {
        #pragma unroll 8
        for (int i = 0; i < 64; ++i) {
            bf16x8 a = Ap[i * 4];
            bf16x8 b = Bp[i * 64];
            acc = __builtin_amdgcn_mfma_f32_16x16x32_bf16(a, b, acc, 0, 0, 0);
        }
    }

    // epilogue: C/D layout col=lane&15, row=(lane>>4)*4+r
    #pragma unroll
    for (int r = 0; r < 4; ++r) {
        int m   = m0 + w * 16 + q * 4 + r;
        int tok = x[(size_t)m * LL + t];
        float v = acc[r] + projE[(size_t)tok * HH + n];
        v = fminf(fmaxf(v, -15.f), 15.f);
        float e2 = __expf(2.f * v);
        float hv = (e2 - 1.f) / (e2 + 1.f);   // tanh
        hn[(size_t)m * HH + n] = f2bf(hv);
        if (t == LL - 1) out_final[(size_t)m * HH + n] = hv;
    }
    if (duty) {
        float by = b_y[n0 + col];
        #pragma unroll
        for (int r = 0; r < 4; ++r) {
            int m = m0 + w * 16 + q * 4 + r;
            out_logits[(size_t)m * (LL * VV) + (size_t)(t - 1) * VV + n0 + col]
                = accL[r] + by;
        }
    }
}

// ---------------------------------------------------------------------------
// Final logits (position LL-1) from h_512 (ping buffer 0). 12 blocks.
// ---------------------------------------------------------------------------
__global__ __launch_bounds__(256)
void logits_last(const unsigned short* __restrict__ h,
                 const unsigned short* __restrict__ w_hy_frag,
                 const float* __restrict__ b_y, float* __restrict__ out_logits)
{
    const int tid  = threadIdx.x;
    const int bm   = blockIdx.x / 6;
    const int vt   = blockIdx.x % 6;
    const int m0   = bm * 64;

    const int w    = tid >> 6;
    const int lane = tid & 63;
    const int col  = lane & 15;
    const int q    = lane >> 4;
    const int am   = m0 + w * 16 + col;

    const bf16x8* Ap  = (const bf16x8*)(h + (size_t)am * HH + q * 8);
    const bf16x8* Hyp = (const bf16x8*)w_hy_frag + (size_t)vt * 4096 + lane;

    f32x4 acc = {0.f, 0.f, 0.f, 0.f};
    #pragma unroll 8
    for (int i = 0; i < 64; ++i) {
        bf16x8 a  = Ap[i * 4];
        bf16x8 bl = Hyp[i * 64];
        acc = __builtin_amdgcn_mfma_f32_16x16x32_bf16(a, bl, acc, 0, 0, 0);
    }
    float by = b_y[vt * 16 + col];
    #pragma unroll
    for (int r = 0; r < 4; ++r) {
        int m = m0 + w * 16 + q * 4 + r;
        out_logits[(size_t)m * (LL * VV) + (size_t)(LL - 1) * VV + vt * 16 + col]
            = acc[r] + by;
    }
}

extern "C" void kernel_launch(void* const* d_in, const int* in_sizes, int n_in,
                              void* d_out, int out_size, void* d_ws, size_t ws_size,
                              hipStream_t stream) {
    const int*   x      = (const int*)  d_in[0];
    const float* hidden = (const float*)d_in[1];
    const float* emb    = (const float*)d_in[2];
    const float* W_xh   = (const float*)d_in[3];
    const float* W_hh   = (const float*)d_in[4];
    const float* b_h    = (const float*)d_in[5];
    const float* W_hy   = (const float*)d_in[6];
    const float* b_y    = (const float*)d_in[7];

    float* out_logits = (float*)d_out;                          // [B][L][V]
    float* out_final  = out_logits + (size_t)BB * LL * VV;      // [B][H]

    // workspace (~10.3 MB): 8 MB w_hh_frag + 384 KB w_hy_frag + 768 KB projE
    // + 1 MB h ping-pong
    char* ws = (char*)d_ws;
    unsigned short* w_hh_frag = (unsigned short*)ws;                       // 8 MB
    unsigned short* w_hy_frag = (unsigned short*)(ws + 8388608);           // 384 KB
    float* projE              = (float*)(ws + 8388608 + 393216);           // 768 KB
    unsigned short* hbuf      = (unsigned short*)(ws + 8388608 + 393216 + 786432);

    setup_kernel<<<dim3(1024), dim3(256), 0, stream>>>(
        x, hidden, emb, W_xh, W_hh, b_h, W_hy,
        projE, w_hh_frag, w_hy_frag, hbuf);

    for (int t = 0; t < LL; ++t) {
        const unsigned short* hp = hbuf + (size_t)(t & 1) * BBHH;
        unsigned short*       hn = hbuf + (size_t)((t + 1) & 1) * BBHH;
        step_kernel<<<dim3(256), dim3(256), 0, stream>>>(
            x, projE, w_hh_frag, w_hy_frag, b_y, hp, hn,
            out_logits, out_final, t);
    }
    // h_512 lives in ping buffer 0 after 512 steps
    logits_last<<<dim3(12), dim3(256), 0, stream>>>(
        hbuf, w_hy_frag, b_y, out_logits);
}